// Round 8
// baseline (525.905 us; speedup 1.0000x reference)
//
#include <hip/hip_runtime.h>

typedef unsigned int u32;
typedef unsigned short u16;
typedef __attribute__((ext_vector_type(8))) short bf16x8;   // 8 bf16 in 4 VGPRs
typedef __attribute__((ext_vector_type(4))) float f32x4;

#define GLOBAL_AS __attribute__((address_space(1)))
#define LDS_AS    __attribute__((address_space(3)))

#define B_   64
#define T_   256
#define E_   1024
#define H_   16
#define HD_  64
#define NTOK (B_*T_)          // 16384
#define K_   1024
#define LNEPS 1e-5f

// ---------- bf16 helpers ----------
__device__ __forceinline__ float bf2f(u16 u){ return __uint_as_float(((u32)u) << 16); }
__device__ __forceinline__ u16 f2bf(float f){            // round-to-nearest-even
  u32 x = __float_as_uint(f);
  u32 r = x + 0x7fffu + ((x >> 16) & 1u);
  return (u16)(r >> 16);
}
__device__ __forceinline__ u16 f2bf_trunc(float f){      // truncate (P probs only)
  return (u16)(__float_as_uint(f) >> 16);
}
__device__ __forceinline__ u32 pack2(float a, float b){
  return (u32)f2bf(a) | ((u32)f2bf(b) << 16);
}

// async global->LDS, 16 B per lane (dest = wave-uniform base + lane*16)
__device__ __forceinline__ void gload16(const u16* g, u16* l){
  __builtin_amdgcn_global_load_lds((const GLOBAL_AS void*)g, (LDS_AS void*)l, 16, 0, 0);
}

// ---------- prep mega-kernel: weight transposes + LN1, one dispatch ----------
// blocks [0,768): qkv weights; [768,1536): wproj/w1/w2 transpose; [1536,5632): LN1
__global__ __launch_bounds__(256) void prep_kernel(
    const float* __restrict__ wk, const float* __restrict__ wq,
    const float* __restrict__ wv, const float* __restrict__ wproj,
    const float* __restrict__ w1, const float* __restrict__ w2,
    const float* __restrict__ x, const float* __restrict__ g1,
    const float* __restrict__ be1,
    u16* __restrict__ wqkvT, u16* __restrict__ wprojT,
    u16* __restrict__ w1T, u16* __restrict__ w2T, u16* __restrict__ hb)
{
  __shared__ float tile[64 * 68];
  const int bid = blockIdx.x, t = threadIdx.x;
  if (bid < 768) {
    // qkv: out[n][e], n = z*1024 + h*64 + d
    const int zh = bid >> 4, z = zh >> 4, h = zh & 15;
    const int e0 = (bid & 15) << 6;
    const float* w = (z == 0 ? wk : z == 1 ? wq : wv) + (size_t)h * (E_ * HD_);
    {
      int er = t >> 2, d0 = (t & 3) << 4;
      const float4* src = (const float4*)(w + (size_t)(e0 + er) * HD_ + d0);
      #pragma unroll
      for (int i = 0; i < 4; ++i)
        *(float4*)(tile + er * 68 + d0 + 4 * i) = src[i];
    }
    __syncthreads();
    {
      int dr = t >> 2, ee = (t & 3) << 4;
      u32 wd[8];
      #pragma unroll
      for (int j = 0; j < 8; ++j)
        wd[j] = pack2(tile[(ee + 2*j) * 68 + dr], tile[(ee + 2*j + 1) * 68 + dr]);
      u16* dst = wqkvT + (size_t)(z * 1024 + h * 64 + dr) * K_ + e0 + ee;
      *(uint4*)(dst    ) = make_uint4(wd[0], wd[1], wd[2], wd[3]);
      *(uint4*)(dst + 8) = make_uint4(wd[4], wd[5], wd[6], wd[7]);
    }
  } else if (bid < 1536) {
    const int r = bid - 768, wsel = r >> 8, within = r & 255;
    const float* w = (wsel == 0 ? wproj : wsel == 1 ? w1 : w2);
    u16* o = (wsel == 0 ? wprojT : wsel == 1 ? w1T : w2T);
    const int n0 = (within & 15) << 6, k0 = (within >> 4) << 6;
    {
      int kr = t >> 2, nn = (t & 3) << 4;
      const float4* src = (const float4*)(w + (size_t)(k0 + kr) * E_ + n0 + nn);
      #pragma unroll
      for (int i = 0; i < 4; ++i)
        *(float4*)(tile + kr * 68 + nn + 4 * i) = src[i];
    }
    __syncthreads();
    {
      int nr = t >> 2, kk = (t & 3) << 4;
      u32 wd[8];
      #pragma unroll
      for (int j = 0; j < 8; ++j)
        wd[j] = pack2(tile[(kk + 2*j) * 68 + nr], tile[(kk + 2*j + 1) * 68 + nr]);
      u16* dst = o + (size_t)(n0 + nr) * K_ + k0 + kk;
      *(uint4*)(dst    ) = make_uint4(wd[0], wd[1], wd[2], wd[3]);
      *(uint4*)(dst + 8) = make_uint4(wd[4], wd[5], wd[6], wd[7]);
    }
  } else {
    // LN1 (fp32 in -> bf16 out), one wave per token
    int lane  = t & 63;
    int token = ((bid - 1536) << 2) + (t >> 6);
    const float4* xr = (const float4*)(x + (size_t)token * E_);
    float4 v[4];
    float s = 0.f, ss = 0.f;
    #pragma unroll
    for (int i = 0; i < 4; ++i){
      v[i] = xr[lane + 64 * i];
      s += v[i].x + v[i].y + v[i].z + v[i].w;
      ss = fmaf(v[i].x, v[i].x, fmaf(v[i].y, v[i].y,
           fmaf(v[i].z, v[i].z, fmaf(v[i].w, v[i].w, ss))));
    }
    #pragma unroll
    for (int off = 32; off > 0; off >>= 1){
      s  += __shfl_xor(s,  off);
      ss += __shfl_xor(ss, off);
    }
    float mu   = s * (1.f / E_);
    float var  = ss * (1.f / E_) - mu * mu;
    float rstd = rsqrtf(var + LNEPS);
    const float4* gr = (const float4*)g1;
    const float4* br = (const float4*)be1;
    uint2* orow = (uint2*)(hb + (size_t)token * E_);
    #pragma unroll
    for (int i = 0; i < 4; ++i){
      float4 gg = gr[lane + 64 * i], bb = br[lane + 64 * i];
      float y0 = (v[i].x - mu) * rstd * gg.x + bb.x;
      float y1 = (v[i].y - mu) * rstd * gg.y + bb.y;
      float y2 = (v[i].z - mu) * rstd * gg.z + bb.z;
      float y3 = (v[i].w - mu) * rstd * gg.w + bb.w;
      orow[lane + 64 * i] = make_uint2(pack2(y0, y1), pack2(y2, y3));
    }
  }
}

// ---------- LN2: bf16 in -> bf16 out, one wave per token ----------
__global__ __launch_bounds__(256) void ln2_kernel(
    const u16* __restrict__ x1, const float* __restrict__ g,
    const float* __restrict__ b, u16* __restrict__ o)
{
  int lane  = threadIdx.x & 63;
  int token = (blockIdx.x << 2) + (threadIdx.x >> 6);
  const uint4* xr = (const uint4*)(x1 + (size_t)token * E_);
  float f[16];
  float s = 0.f, ss = 0.f;
  #pragma unroll
  for (int i = 0; i < 2; ++i){
    uint4 u = xr[lane * 2 + i];
    u32 w[4] = {u.x, u.y, u.z, u.w};
    #pragma unroll
    for (int j = 0; j < 4; ++j){
      f[i*8 + 2*j    ] = __uint_as_float(w[j] << 16);
      f[i*8 + 2*j + 1] = __uint_as_float(w[j] & 0xffff0000u);
    }
  }
  #pragma unroll
  for (int j = 0; j < 16; ++j){ s += f[j]; ss = fmaf(f[j], f[j], ss); }
  #pragma unroll
  for (int off = 32; off > 0; off >>= 1){
    s  += __shfl_xor(s,  off);
    ss += __shfl_xor(ss, off);
  }
  float mu   = s * (1.f / E_);
  float var  = ss * (1.f / E_) - mu * mu;
  float rstd = rsqrtf(var + LNEPS);
  const float4* gr = (const float4*)g;
  const float4* br = (const float4*)b;
  u32 wd[8];
  #pragma unroll
  for (int i = 0; i < 4; ++i){
    float4 gg = gr[lane * 4 + i], bb = br[lane * 4 + i];
    float y0 = (f[4*i    ] - mu) * rstd * gg.x + bb.x;
    float y1 = (f[4*i + 1] - mu) * rstd * gg.y + bb.y;
    float y2 = (f[4*i + 2] - mu) * rstd * gg.z + bb.z;
    float y3 = (f[4*i + 3] - mu) * rstd * gg.w + bb.w;
    wd[2*i]   = pack2(y0, y1);
    wd[2*i+1] = pack2(y2, y3);
  }
  uint4* orow = (uint4*)(o + (size_t)token * E_ + lane * 16);
  orow[0] = make_uint4(wd[0], wd[1], wd[2], wd[3]);
  orow[1] = make_uint4(wd[4], wd[5], wd[6], wd[7]);
}

// ---------- MFMA GEMM: C(M x N) = A(M x 1024) * Bt(N x 1024)^T ----------
// 128x128 tile / 256 threads, BK=64. Grid: x = col-block (fastest -> L2/L3
// locality on the shared A row-block), y = row-block.
// LDS rows are 8 chunks of 16 B, XOR-swizzled: slot chunk = chunk ^ (row&7).
// MODE 0: qkv -> k,q bf16 (b,h,t,d); v bf16 TRANSPOSED (b,h,d,t)
// MODE 1: proj -> Cb bf16 = acc + bias + residf(fp32), LDS-transposed stores
// MODE 2: ff1  -> Cb bf16 = relu(acc + bias), LDS-transposed stores
// MODE 3: ff2  -> Cf fp32 = acc + bias + residb(bf16)    [row-major]
template<int MODE>
__global__ __launch_bounds__(256) void mgemm_kernel(
    const u16* __restrict__ A, const u16* __restrict__ Bt,
    const float* __restrict__ bias, const float* __restrict__ residf,
    const u16* __restrict__ residb,
    float* __restrict__ Cf, u16* __restrict__ Cb, u16* __restrict__ Cb2)
{
  __shared__ __align__(16) u16 lds[16384];     // 32 KB: As | Bs, reused by epilogue
  u16* As = lds;                               // [128 rows][64 k] swizzled
  u16* Bs = lds + 8192;
  const int row0 = blockIdx.y * 128, col0 = blockIdx.x * 128;
  const int tid = threadIdx.x, lane = tid & 63;
  const int wv_ = tid >> 6, wm = wv_ >> 1, wn = wv_ & 1;
  const int l15 = lane & 15, quad = lane >> 4;

  const int srow   = tid >> 3;
  const int schunk = ((tid & 7) ^ ((tid >> 3) & 7)) << 3;
  const u16* Ag = A  + (size_t)(row0 + srow) * K_ + schunk;
  const u16* Bg = Bt + (size_t)(col0 + srow) * K_ + schunk;
  u16* Ald = As + tid * 8;
  u16* Bld = Bs + tid * 8;

  f32x4 acc[4][4];
  #pragma unroll
  for (int i = 0; i < 4; ++i)
    #pragma unroll
    for (int j = 0; j < 4; ++j)
      acc[i][j] = (f32x4){0.f, 0.f, 0.f, 0.f};

  const int mrow = wm * 64, nrow = wn * 64;
  for (int k0 = 0; k0 < K_; k0 += 64) {
    __syncthreads();
    #pragma unroll
    for (int p = 0; p < 4; ++p) {
      gload16(Ag + (size_t)(p * 32) * K_ + k0, Ald + p * 2048);
      gload16(Bg + (size_t)(p * 32) * K_ + k0, Bld + p * 2048);
    }
    __syncthreads();
    #pragma unroll
    for (int ss = 0; ss < 2; ++ss) {
      bf16x8 a[4], b[4];
      #pragma unroll
      for (int i = 0; i < 4; ++i){
        int ma = mrow + i * 16 + l15, nb = nrow + i * 16 + l15;
        a[i] = *(const bf16x8*)(As + ma * 64 + ((((ss << 2) | quad)) ^ (ma & 7)) * 8);
        b[i] = *(const bf16x8*)(Bs + nb * 64 + ((((ss << 2) | quad)) ^ (nb & 7)) * 8);
      }
      #pragma unroll
      for (int i = 0; i < 4; ++i)
        #pragma unroll
        for (int j = 0; j < 4; ++j)
          acc[i][j] = __builtin_amdgcn_mfma_f32_16x16x32_bf16(a[i], b[j], acc[i][j], 0, 0, 0);
    }
  }

  if (MODE == 3) {
    // fp32 row-major epilogue, resid bf16 (coalesced dword stores)
    #pragma unroll
    for (int j = 0; j < 4; ++j) {
      const int n = col0 + wn * 64 + j * 16 + l15;
      float bn = bias[n];
      #pragma unroll
      for (int i = 0; i < 4; ++i)
        #pragma unroll
        for (int r = 0; r < 4; ++r) {
          const int row = row0 + wm * 64 + i * 16 + quad * 4 + r;
          size_t idx = (size_t)row * E_ + n;
          Cf[idx] = acc[i][j][r] + bn + bf2f(residb[idx]);
        }
    }
    return;
  }

  // ---- bf16 epilogues via per-wave 8-KB LDS transpose -> 16-B coalesced stores ----
  __syncthreads();                              // everyone done with As/Bs
  u16* ep = lds + wv_ * 4096;                   // 64x64 u16, row stride 64
  const int nb0 = col0 + wn * 64;               // wave's 64-col window (64-aligned)

  if (MODE == 1 || MODE == 2) {
    #pragma unroll
    for (int j = 0; j < 4; ++j) {
      float bn = bias[nb0 + j * 16 + l15];
      #pragma unroll
      for (int i = 0; i < 4; ++i)
        #pragma unroll
        for (int r = 0; r < 4; ++r) {
          float v = acc[i][j][r] + bn;
          if (MODE == 1) {
            const int row = row0 + wm * 64 + i * 16 + quad * 4 + r;
            v += residf[(size_t)row * E_ + nb0 + j * 16 + l15];
          } else {
            v = fmaxf(v, 0.f);
          }
          ep[(i*16 + quad*4 + r) * 64 + j*16 + l15] = f2bf(v);
        }
    }
    __syncthreads();
    const int rbase = row0 + wm * 64;
    #pragma unroll
    for (int it = 0; it < 8; ++it) {
      int tl = it * 8 + (lane >> 3), c = lane & 7;
      uint4 v = *(const uint4*)(ep + tl * 64 + c * 8);
      *(uint4*)(Cb + (size_t)(rbase + tl) * E_ + nb0 + c * 8) = v;
    }
    return;
  }

  // MODE 0: z = 0 (k), 1 (q): row-major (b,h,t,d). z = 2 (v): transposed (b,h,d,t).
  const int z = nb0 >> 10, h = (nb0 >> 6) & 15;
  const int bb = (row0 + wm * 64) >> 8, tb0 = (row0 + wm * 64) & 255;
  if (z < 2) {
    #pragma unroll
    for (int i = 0; i < 4; ++i)
      #pragma unroll
      for (int j = 0; j < 4; ++j)
        #pragma unroll
        for (int r = 0; r < 4; ++r)
          ep[(i*16 + quad*4 + r) * 64 + j*16 + l15] = f2bf(acc[i][j][r]);
  } else {
    // write transposed [d][t], chunk-swizzled to break the 16-way write conflict
    #pragma unroll
    for (int i = 0; i < 4; ++i)
      #pragma unroll
      for (int j = 0; j < 4; ++j)
        #pragma unroll
        for (int r = 0; r < 4; ++r) {
          int tl = i*16 + quad*4 + r, d = j*16 + l15;
          int cs = (tl >> 3) ^ (d & 7);
          ep[d * 64 + cs * 8 + (tl & 7)] = f2bf(acc[i][j][r]);
        }
  }
  __syncthreads();
  if (z < 2) {
    u16* out = (z == 0 ? Cb : Cb2) + ((size_t)(bb * H_ + h) * T_ + tb0) * HD_;
    #pragma unroll
    for (int it = 0; it < 8; ++it) {
      int tl = it * 8 + (lane >> 3), c = lane & 7;
      uint4 v = *(const uint4*)(ep + tl * 64 + c * 8);
      *(uint4*)(out + (size_t)tl * HD_ + c * 8) = v;
    }
  } else {
    u16* out = (u16*)Cf + ((size_t)(bb * H_ + h) * HD_) * T_;
    #pragma unroll
    for (int it = 0; it < 8; ++it) {
      int dl = it * 8 + (lane >> 3), c = lane & 7;
      int cs = c ^ (dl & 7);
      uint4 v = *(const uint4*)(ep + dl * 64 + cs * 8);
      *(uint4*)(out + (size_t)dl * T_ + tb0 + c * 8) = v;
    }
  }
}

// ---------- MFMA flash attention: block = 4 bh's at one tblk (balanced waves) ----------
// scores[t][s] = k_t . q_s / 8 (K.Q^T per reference), causal s<=t.
// k,q bf16 (b,h,t,d); vt bf16 (b,h,d,t); out bf16 row-major (b,t,h*64+d).
__global__ __launch_bounds__(256) void fattn_kernel(
    const u16* __restrict__ kk_, const u16* __restrict__ qq_,
    const u16* __restrict__ vt_, u16* __restrict__ out)
{
  __shared__ __align__(16) u16 Pb[4][64 * 72];  // per-wave private, 9216 B each
  const int tid = threadIdx.x, lane = tid & 63, wv = tid >> 6;
  const int bh = blockIdx.x * 4 + wv;
  const int tblk = blockIdx.y;
  const int l15 = lane & 15, quad = lane >> 4;
  const u16* kb  = kk_ + (size_t)bh * (T_ * HD_);
  const u16* qb  = qq_ + (size_t)bh * (T_ * HD_);
  const u16* vtb = vt_ + (size_t)bh * (HD_ * T_);
  u16* Pw = Pb[wv];

  bf16x8 kf[4][2];
  #pragma unroll
  for (int i = 0; i < 4; ++i)
    #pragma unroll
    for (int c = 0; c < 2; ++c)
      kf[i][c] = *(const bf16x8*)(kb + (size_t)(tblk*64 + i*16 + l15) * HD_ + c*32 + quad*8);

  f32x4 o[4][4];
  float mrow[4][4], lrow[4][4];
  #pragma unroll
  for (int i = 0; i < 4; ++i) {
    #pragma unroll
    for (int j = 0; j < 4; ++j) o[i][j] = (f32x4){0.f, 0.f, 0.f, 0.f};
    #pragma unroll
    for (int r = 0; r < 4; ++r) { mrow[i][r] = -1e30f; lrow[i][r] = 0.f; }
  }

  for (int sb = 0; sb <= tblk; ++sb) {        // trip count uniform per block
    f32x4 S[4][4];
    #pragma unroll
    for (int j = 0; j < 4; ++j) {
      bf16x8 qf0 = *(const bf16x8*)(qb + (size_t)(sb*64 + j*16 + l15) * HD_ +      quad*8);
      bf16x8 qf1 = *(const bf16x8*)(qb + (size_t)(sb*64 + j*16 + l15) * HD_ + 32 + quad*8);
      #pragma unroll
      for (int i = 0; i < 4; ++i) {
        f32x4 t0 = __builtin_amdgcn_mfma_f32_16x16x32_bf16(kf[i][0], qf0,
                       (f32x4){0.f,0.f,0.f,0.f}, 0, 0, 0);
        S[i][j] = __builtin_amdgcn_mfma_f32_16x16x32_bf16(kf[i][1], qf1, t0, 0, 0, 0);
      }
    }
    #pragma unroll
    for (int i = 0; i < 4; ++i)
      #pragma unroll
      for (int j = 0; j < 4; ++j)
        #pragma unroll
        for (int r = 0; r < 4; ++r) {
          float val = S[i][j][r] * 0.125f;
          if (sb == tblk) {
            int tl = i*16 + quad*4 + r, sl = j*16 + l15;
            if (sl > tl) val = -1e30f;
          }
          S[i][j][r] = val;
        }
    #pragma unroll
    for (int i = 0; i < 4; ++i)
      #pragma unroll
      for (int r = 0; r < 4; ++r) {
        float mx = fmaxf(fmaxf(S[i][0][r], S[i][1][r]), fmaxf(S[i][2][r], S[i][3][r]));
        #pragma unroll
        for (int msk = 1; msk < 16; msk <<= 1) mx = fmaxf(mx, __shfl_xor(mx, msk));
        float mn = fmaxf(mrow[i][r], mx);
        float al = __expf(mrow[i][r] - mn);
        mrow[i][r] = mn;
        float sm = 0.f;
        #pragma unroll
        for (int j = 0; j < 4; ++j) {
          float p = __expf(S[i][j][r] - mn);
          S[i][j][r] = p;
          sm += p;
        }
        #pragma unroll
        for (int msk = 1; msk < 16; msk <<= 1) sm += __shfl_xor(sm, msk);
        lrow[i][r] = lrow[i][r] * al + sm;
        #pragma unroll
        for (int jd = 0; jd < 4; ++jd) o[i][jd][r] *= al;
      }
    #pragma unroll
    for (int i = 0; i < 4; ++i)
      #pragma unroll
      for (int j = 0; j < 4; ++j)
        #pragma unroll
        for (int r = 0; r < 4; ++r)
          Pw[(i*16 + quad*4 + r) * 72 + j*16 + l15] = f2bf_trunc(S[i][j][r]);
    __syncthreads();
    bf16x8 pf[4][2];
    #pragma unroll
    for (int i = 0; i < 4; ++i)
      #pragma unroll
      for (int c = 0; c < 2; ++c)
        pf[i][c] = *(const bf16x8*)(Pw + (i*16 + l15) * 72 + c*32 + quad*8);
    #pragma unroll
    for (int jd = 0; jd < 4; ++jd) {
      bf16x8 vf0 = *(const bf16x8*)(vtb + (size_t)(jd*16 + l15) * T_ + sb*64 +      quad*8);
      bf16x8 vf1 = *(const bf16x8*)(vtb + (size_t)(jd*16 + l15) * T_ + sb*64 + 32 + quad*8);
      #pragma unroll
      for (int i = 0; i < 4; ++i) {
        f32x4 t0 = __builtin_amdgcn_mfma_f32_16x16x32_bf16(pf[i][0], vf0, o[i][jd], 0, 0, 0);
        o[i][jd] = __builtin_amdgcn_mfma_f32_16x16x32_bf16(pf[i][1], vf1, t0, 0, 0, 0);
      }
    }
    __syncthreads();
  }

  #pragma unroll
  for (int i = 0; i < 4; ++i)
    #pragma unroll
    for (int r = 0; r < 4; ++r) {
      float inv = 1.0f / lrow[i][r];
      #pragma unroll
      for (int jd = 0; jd < 4; ++jd)
        Pw[(i*16 + quad*4 + r) * 72 + jd*16 + l15] = f2bf(o[i][jd][r] * inv);
    }
  __syncthreads();
  {
    const int b = bh >> 4, h = bh & 15;
    const uint4* pr = (const uint4*)(Pw + lane * 72);
    uint4* og = (uint4*)(out + ((size_t)(b * T_ + tblk*64 + lane)) * E_ + h * HD_);
    #pragma unroll
    for (int k = 0; k < 8; ++k) og[k] = pr[k];
  }
}

// ---------- launch ----------
extern "C" void kernel_launch(void* const* d_in, const int* in_sizes, int n_in,
                              void* d_out, int out_size, void* d_ws, size_t ws_size,
                              hipStream_t stream) {
  const float* x     = (const float*)d_in[0];
  const float* ln1g  = (const float*)d_in[1];
  const float* ln1b  = (const float*)d_in[2];
  const float* wk    = (const float*)d_in[3];
  const float* wq    = (const float*)d_in[4];
  const float* wv    = (const float*)d_in[5];
  const float* wproj = (const float*)d_in[6];
  const float* bproj = (const float*)d_in[7];
  const float* ln2g  = (const float*)d_in[8];
  const float* ln2b  = (const float*)d_in[9];
  const float* w1    = (const float*)d_in[10];
  const float* b1    = (const float*)d_in[11];
  const float* w2    = (const float*)d_in[12];
  const float* b2    = (const float*)d_in[13];
  float* outp = (float*)d_out;

  // ws (112 MB <= proven 128 MB):
  //  [0,6M) WqkvT | [6,8M) WprojT | [8,10M) W1T | [10,12M) W2T
  //  hb  [16,48M): LN1-out -> (qkv) -> attn-out -> (proj) -> ff1-out -> (ff2)
  //  kbuf[48,80M): k (bhtd) -> (fattn) -> x1 bf16 -> (ln2, ff2 resid)
  //  qbuf[80,112M): q (bhtd) -> (fattn) -> h2 bf16 -> (ff1)
  // d_out: v^T bf16 (b,h,d,t) [0,32M) -> final out fp32 (full 64M)
  char* ws = (char*)d_ws;
  const size_t MB = 1024 * 1024;
  u16* wqkvT  = (u16*)(ws);
  u16* wprojT = (u16*)(ws + 6 * MB);
  u16* w1T    = (u16*)(ws + 8 * MB);
  u16* w2T    = (u16*)(ws + 10 * MB);
  u16* hb     = (u16*)(ws + 16 * MB);
  u16* kbuf   = (u16*)(ws + 48 * MB);
  u16* qbuf   = (u16*)(ws + 80 * MB);
  u16* vtbuf  = (u16*)d_out;                   // v^T (b,h,d,t) bf16

  // 0) prep: weight transposes + LN1 (one dispatch)
  prep_kernel<<<5632, 256, 0, stream>>>(wk, wq, wv, wproj, w1, w2,
                                        x, ln1g, ln1b,
                                        wqkvT, wprojT, w1T, w2T, hb);
  // 1) k,q bf16 (bhtd) + v^T bf16 (bhdt, d_out) = hb @ WqkvT^T
  mgemm_kernel<0><<<dim3(3*E_/128, NTOK/128), 256, 0, stream>>>(
      hb, wqkvT, nullptr, nullptr, nullptr, (float*)vtbuf, kbuf, qbuf);
  // 2) MFMA flash attention (balanced) -> bf16 row-major into hb
  fattn_kernel<<<dim3(B_*H_/4, 4), 256, 0, stream>>>(kbuf, qbuf, vtbuf, hb);
  // 3) x1 bf16 = x + attn @ wproj + bproj -> kbuf (k dead)
  mgemm_kernel<1><<<dim3(E_/128, NTOK/128), 256, 0, stream>>>(
      hb, wprojT, bproj, x, nullptr, nullptr, kbuf, nullptr);
  // 4) h2 bf16 = LN2(x1) -> qbuf (q dead)
  ln2_kernel<<<NTOK/4, 256, 0, stream>>>(kbuf, ln2g, ln2b, qbuf);
  // 5) ff1 bf16 = relu(h2 @ w1 + b1) -> hb (attn dead)
  mgemm_kernel<2><<<dim3(E_/128, NTOK/128), 256, 0, stream>>>(
      qbuf, w1T, b1, nullptr, nullptr, nullptr, hb, nullptr);
  // 6) out fp32 = x1 + ff1 @ w2 + b2 -> d_out
  mgemm_kernel<3><<<dim3(E_/128, NTOK/128), 256, 0, stream>>>(
      hb, w2T, b2, nullptr, kbuf, outp, nullptr, nullptr);
}